// Round 3
// baseline (152.464 us; speedup 1.0000x reference)
//
#include <hip/hip_runtime.h>

#define N_EL   15
#define NPAIR  105     // 15*14/2 unique pairs
#define BASIS  64
#define CUTOFF 10.0f
#define LOG_HALF (-0.69314718055994531f)
#define LOG2E    1.44269504088896340736f
#define LN2      0.69314718055994530942f
#define PPB    3       // problems per block
#define NTHR   320     // 5 waves; 3*105 = 315 pair threads active (98.4%)

typedef float f32x2 __attribute__((ext_vector_type(2)));
typedef float f32x4 __attribute__((ext_vector_type(4)));

// guaranteed packed FMA: d = a*b + d  (also pins d in VGPRs)
__device__ __forceinline__ void pk_fma(f32x2& d, f32x2 a, f32x2 b) {
    asm("v_pk_fma_f32 %0, %1, %2, %0" : "+v"(d) : "v"(a), "v"(b));
}

// fast shifted softplus: log(0.5 + 0.5*e^x) = ln2 * log2(0.5 + 0.5*2^(x*log2e))
// safe here: |x| provably < 20 for this problem's weight scales
__device__ __forceinline__ float ssp(float x) {
    float u = __builtin_amdgcn_exp2f(x * LOG2E);
    return LN2 * __builtin_amdgcn_logf(fmaf(0.5f, u, 0.5f));
}

__global__ __launch_bounds__(NTHR, 4)
void backflow_kernel(const float* __restrict__ rs,
                     const float* __restrict__ W0,
                     const float* __restrict__ b0,
                     const float* __restrict__ W1,
                     const float* __restrict__ b1,
                     const float* __restrict__ W2,
                     float* __restrict__ out, int nprob) {
    __shared__ f32x4  s_w0[3 * BASIS * 4];   // W0: 3 x 64 rows x 16 cols (4 float4/row)
    __shared__ f32x4  s_w1[3 * 16];          // W1: 3 x 16 rows x 4 cols
    __shared__ f32x2  s_mu[BASIS / 2];       // paired mus
    __shared__ f32x2  s_is[BASIS / 2];       // paired -log2e/sigma^2
    __shared__ float  s_xs[PPB][N_EL * 3];   // coordinates
    __shared__ float  s_wd[PPB][NPAIR * 3];  // per unique pair: w * diff

    const int tid = threadIdx.x;

    // stage all weights once (uniform across problems)
    {
        const f32x4* W0v = (const f32x4*)W0;
        for (int f = tid; f < 3 * BASIS * 4; f += NTHR) s_w0[f] = W0v[f];
        const f32x4* W1v = (const f32x4*)W1;
        if (tid < 3 * 16) s_w1[tid] = W1v[tid];
    }
    // distance-basis constants, two basis dims per entry
    if (tid < BASIS / 2) {
        f32x2 mu, is;
        #pragma unroll
        for (int h = 0; h < 2; ++h) {
            int d = 2 * tid + h;
            float q  = (float)(2 * d + 1) * (1.0f / 128.0f);
            float m  = CUTOFF * q * q;
            float sg = fmaf(CUTOFF, q, 1.0f) * (1.0f / 7.0f);
            mu[h] = m;
            is[h] = -LOG2E / (sg * sg);
        }
        s_mu[tid] = mu; s_is[tid] = is;
    }

    // coordinate staging: threads 0..134 load 45 floats for each of 3 problems
    const int q2 = tid / 45, e3 = tid - 45 * q2;
    const int P2 = blockIdx.x * PPB + q2;
    const bool io_ok = (tid < PPB * 45) && (P2 < nprob);
    if (io_ok) s_xs[q2][e3] = rs[P2 * 45 + e3];

    // pair work mapping: thread -> (problem q, unique pair pr)
    const int q  = tid / NPAIR;
    const int pr = tid - NPAIR * q;
    const bool valid = (q < PPB) && (blockIdx.x * PPB + q < nprob);

    // decode unique pair (pi < pj) from pr (row-major upper triangle)
    int pi = 0, pj = 0;
    {
        int t = pr, i = 0;
        while (t >= (N_EL - 1 - i)) { t -= (N_EL - 1 - i); ++i; }
        pi = i; pj = i + 1 + t;
    }
    __syncthreads();

    for (int k = 0; k < 3; ++k) {
        const f32x4* w0k = s_w0 + k * BASIS * 4;
        const f32x4* w1k = s_w1 + k * 16;
        const float* b0k = b0 + k * 16;
        const float* b1k = b1 + k * 4;
        const float* W2k = W2 + k * 4;

        if (valid) {
            float dx = s_xs[q][pj * 3 + 0] - s_xs[q][pi * 3 + 0];
            float dy = s_xs[q][pj * 3 + 1] - s_xs[q][pi * 3 + 1];
            float dz = s_xs[q][pj * 3 + 2] - s_xs[q][pi * 3 + 2];
            float dist = sqrtf(fmaf(dx, dx, fmaf(dy, dy, dz * dz)));

            float x = dist * (1.0f / CUTOFF);
            float env = 0.0f;
            if (x <= 1.0f) {
                float p = fmaf(-6.0f, x, 15.0f);
                p = fmaf(p, x, -10.0f);
                env = fmaf(x * x * x, p, 1.0f);   // 1 - 10x^3 + 15x^4 - 6x^5
            }

            f32x2 g2[8];
            #pragma unroll
            for (int c = 0; c < 8; ++c) g2[c] = (f32x2)(0.0f);

            if (env > 0.0f) {
                const f32x2 dist2 = {dist, dist};
                #pragma unroll 4
                for (int m = 0; m < BASIS / 2; ++m) {
                    f32x2 t  = dist2 - s_mu[m];          // packed
                    f32x2 a  = (t * t) * s_is[m];        // packed
                    float e0 = __builtin_amdgcn_exp2f(a.x);
                    float e1 = __builtin_amdgcn_exp2f(a.y);
                    const f32x4* row0 = w0k + (2 * m) * 4;
                    const f32x4* row1 = w0k + (2 * m + 1) * 4;
                    f32x2 ev0 = {e0, e0}, ev1 = {e1, e1};
                    #pragma unroll
                    for (int j = 0; j < 4; ++j) {
                        f32x4 w = row0[j];                // LDS broadcast b128
                        pk_fma(g2[2 * j],     ev0, w.xy);
                        pk_fma(g2[2 * j + 1], ev0, w.zw);
                    }
                    #pragma unroll
                    for (int j = 0; j < 4; ++j) {
                        f32x4 w = row1[j];
                        pk_fma(g2[2 * j],     ev1, w.xy);
                        pk_fma(g2[2 * j + 1], ev1, w.zw);
                    }
                }
            }

            // h1 = b0 + env*g  (packed), then layer 1 with packed FMA
            const f32x2* b0v = (const f32x2*)b0k;
            const f32x2 env2 = {env, env};
            f32x2 h2lo = {b1k[0], b1k[1]};
            f32x2 h2hi = {b1k[2], b1k[3]};
            #pragma unroll
            for (int c2 = 0; c2 < 8; ++c2) {
                f32x2 h1v = env2 * g2[c2] + b0v[c2];
                float h0 = ssp(h1v.x);
                float h1 = ssp(h1v.y);
                f32x4 wr0 = w1k[2 * c2];
                f32x4 wr1 = w1k[2 * c2 + 1];
                f32x2 hv0 = {h0, h0}, hv1 = {h1, h1};
                pk_fma(h2lo, hv0, wr0.xy);
                pk_fma(h2hi, hv0, wr0.zw);
                pk_fma(h2lo, hv1, wr1.xy);
                pk_fma(h2hi, hv1, wr1.zw);
            }
            float w = ssp(h2lo.x) * W2k[0];
            w = fmaf(ssp(h2lo.y), W2k[1], w);
            w = fmaf(ssp(h2hi.x), W2k[2], w);
            w = fmaf(ssp(h2hi.y), W2k[3], w);

            s_wd[q][pr * 3 + 0] = w * dx;
            s_wd[q][pr * 3 + 1] = w * dy;
            s_wd[q][pr * 3 + 2] = w * dz;
        }
        __syncthreads();

        // scatter-reduce: electron e gets +w*diff for (e,j>e), -w*diff for (i<e,e)
        if (io_ok) {
            int e = e3 / 3, dim = e3 - 3 * e;
            float acc = 0.0f;
            int offe = e * (2 * N_EL - e - 1) / 2;
            for (int j = e + 1; j < N_EL; ++j)
                acc += s_wd[q2][(offe + j - e - 1) * 3 + dim];
            for (int i2 = 0; i2 < e; ++i2) {
                int p = i2 * (2 * N_EL - i2 - 1) / 2 + (e - i2 - 1);
                acc -= s_wd[q2][p * 3 + dim];
            }
            s_xs[q2][e3] += acc;
        }
        __syncthreads();
    }

    if (io_ok) out[P2 * 45 + e3] = s_xs[q2][e3];
}

extern "C" void kernel_launch(void* const* d_in, const int* in_sizes, int n_in,
                              void* d_out, int out_size, void* d_ws, size_t ws_size,
                              hipStream_t stream) {
    const float* rs = (const float*)d_in[0];
    const float* W0 = (const float*)d_in[1];
    const float* b0 = (const float*)d_in[2];
    const float* W1 = (const float*)d_in[3];
    const float* b1 = (const float*)d_in[4];
    const float* W2 = (const float*)d_in[5];
    float* out = (float*)d_out;

    const int nprob = 4096 * 2;                 // (batch, spin) problems
    dim3 grid((nprob + PPB - 1) / PPB);
    dim3 block(NTHR);
    hipLaunchKernelGGL(backflow_kernel, grid, block, 0, stream,
                       rs, W0, b0, W1, b1, W2, out, nprob);
}

// Round 4
// 81.013 us; speedup vs baseline: 1.8820x; 1.8820x over previous
//
#include <hip/hip_runtime.h>

#define N_EL   15
#define NPAIR  105
#define NPAD   112
#define BASIS  64
#define CUTOFF 10.0f
#define LOG2E  1.44269504088896340736f
#define LN2    0.69314718055994530942f
#define WPB    4        // waves (= problems) per block
#define NTHR   256

typedef float f32x2 __attribute__((ext_vector_type(2)));
typedef float f32x4 __attribute__((ext_vector_type(4)));
typedef short bf16x8 __attribute__((ext_vector_type(8)));

// fp32 -> bf16 with round-to-nearest-even (inputs are finite here)
__device__ __forceinline__ short f2bf(float f) {
    unsigned u = __builtin_bit_cast(unsigned, f);
    u += 0x7FFFu + ((u >> 16) & 1u);
    return (short)(u >> 16);
}

// shifted softplus: log(0.5 + 0.5*e^x); |x| < 40 here, no overflow
__device__ __forceinline__ float ssp(float x) {
    float u = __builtin_amdgcn_exp2f(x * LOG2E);
    return LN2 * __builtin_amdgcn_logf(fmaf(0.5f, u, 0.5f));
}

__global__ __launch_bounds__(NTHR, 4)
void backflow_kernel(const float* __restrict__ rs,
                     const float* __restrict__ W0,
                     const float* __restrict__ b0,
                     const float* __restrict__ W1,
                     const float* __restrict__ b1,
                     const float* __restrict__ W2,
                     float* __restrict__ out) {
    // per-wave private LDS (wave-synchronous; no __syncthreads anywhere)
    __shared__ f32x2 s_dd[WPB][NPAD];   // (dist, env) per pair
    __shared__ f32x4 s_df[WPB][NPAD];   // (dx,dy,dz,_) -> overwritten in place by w*diff
    __shared__ float s_xs[WPB][48];     // coordinates

    const int tid  = threadIdx.x;
    const int q    = tid >> 6;          // wave within block
    const int lane = tid & 63;
    const int g    = lane >> 4;         // 4-lane group
    const int col  = lane & 15;
    const int prob = blockIdx.x * WPB + q;

    // ---- per-lane basis constants: dim(ks,e) = ks*32 + (e>>2)*16 + g*4 + (e&3) ----
    f32x2 mu2[8], is2[8];               // [ks*4 + p], elem pair (2p, 2p+1)
    #pragma unroll
    for (int ks = 0; ks < 2; ++ks)
        #pragma unroll
        for (int p = 0; p < 4; ++p) {
            f32x2 m, s;
            #pragma unroll
            for (int h = 0; h < 2; ++h) {
                int dim = ks * 32 + (p >> 1) * 16 + g * 4 + (p & 1) * 2 + h;
                float qq = (float)(2 * dim + 1) * (1.0f / 128.0f);
                m[h] = CUTOFF * qq * qq;
                float sg = fmaf(CUTOFF, qq, 1.0f) * (1.0f / 7.0f);
                s[h] = -LOG2E / (sg * sg);
            }
            mu2[ks * 4 + p] = m;
            is2[ks * 4 + p] = s;
        }

    // ---- resident weight fragments (bf16) ----
    bf16x8 w0f[3][2];   // A = W0^T : lane holds W0[dim(ks,e)][col]
    bf16x8 w1f[3];      // A = W1^T padded to K=32 : elems<4 = W1[g*4+e][col] (col<4)
    f32x4  b0v[3];      // b0[g*4 + 0..3]
    #pragma unroll
    for (int k = 0; k < 3; ++k) {
        #pragma unroll
        for (int ks = 0; ks < 2; ++ks) {
            bf16x8 v;
            #pragma unroll
            for (int e = 0; e < 8; ++e) {
                int dim = ks * 32 + (e >> 2) * 16 + g * 4 + (e & 3);
                v[e] = f2bf(W0[(k * BASIS + dim) * 16 + col]);
            }
            w0f[k][ks] = v;
        }
        bf16x8 v1;
        #pragma unroll
        for (int e = 0; e < 8; ++e) {
            int c = g * 4 + (e & 3);
            float wv = (e < 4 && col < 4) ? W1[(k * 16 + c) * 4 + col] : 0.0f;
            v1[e] = f2bf(wv);
        }
        w1f[k] = v1;
        b0v[k] = *(const f32x4*)(b0 + k * 16 + g * 4);
    }

    // ---- pair decode (fixed): p0 = lane, p1 = 64+lane (lane < 41) ----
    int pi0, pj0, pi1 = 0, pj1 = 0;
    {
        int t = lane, i = 0;
        while (t >= N_EL - 1 - i) { t -= N_EL - 1 - i; ++i; }
        pi0 = i; pj0 = i + 1 + t;
    }
    if (lane < 41) {
        int t = 64 + lane, i = 0;
        while (t >= N_EL - 1 - i) { t -= N_EL - 1 - i; ++i; }
        pi1 = i; pj1 = i + 1 + t;
    }

    if (lane < 45) s_xs[q][lane] = rs[prob * 45 + lane];

    for (int k = 0; k < 3; ++k) {
        const float* b1k = b1 + k * 4;
        const float* W2k = W2 + k * 4;

        // ---- dist/env/diff phase ----
        {
            float dx = s_xs[q][pj0 * 3 + 0] - s_xs[q][pi0 * 3 + 0];
            float dy = s_xs[q][pj0 * 3 + 1] - s_xs[q][pi0 * 3 + 1];
            float dz = s_xs[q][pj0 * 3 + 2] - s_xs[q][pi0 * 3 + 2];
            float dist = sqrtf(fmaf(dx, dx, fmaf(dy, dy, dz * dz)));
            float x = dist * (1.0f / CUTOFF);
            float env = 0.0f;
            if (x <= 1.0f) {
                float pp = fmaf(-6.0f, x, 15.0f);
                pp = fmaf(pp, x, -10.0f);
                env = fmaf(x * x * x, pp, 1.0f);
            }
            s_dd[q][lane] = (f32x2){dist, env};
            s_df[q][lane] = (f32x4){dx, dy, dz, 0.0f};
        }
        if (lane < 48) {
            if (lane < 41) {
                int p = 64 + lane;
                float dx = s_xs[q][pj1 * 3 + 0] - s_xs[q][pi1 * 3 + 0];
                float dy = s_xs[q][pj1 * 3 + 1] - s_xs[q][pi1 * 3 + 1];
                float dz = s_xs[q][pj1 * 3 + 2] - s_xs[q][pi1 * 3 + 2];
                float dist = sqrtf(fmaf(dx, dx, fmaf(dy, dy, dz * dz)));
                float x = dist * (1.0f / CUTOFF);
                float env = 0.0f;
                if (x <= 1.0f) {
                    float pp = fmaf(-6.0f, x, 15.0f);
                    pp = fmaf(pp, x, -10.0f);
                    env = fmaf(x * x * x, pp, 1.0f);
                }
                s_dd[q][p] = (f32x2){dist, env};
                s_df[q][p] = (f32x4){dx, dy, dz, 0.0f};
            } else {
                // pad pairs 105..111: dist far outside cutoff, env = 0
                s_dd[q][64 + lane] = (f32x2){2.0f * CUTOFF, 0.0f};
            }
        }

        // ---- 7 tiles of 16 pairs ----
        for (int t = 0; t < 7; ++t) {
            f32x2 de = s_dd[q][t * 16 + col];
            float dist = de.x, env = de.y;
            f32x2 d2 = {dist, dist};

            bf16x8 bfrag[2];
            #pragma unroll
            for (int ks = 0; ks < 2; ++ks) {
                bf16x8 v;
                #pragma unroll
                for (int p = 0; p < 4; ++p) {
                    f32x2 tt = d2 - mu2[ks * 4 + p];
                    f32x2 a  = (tt * tt) * is2[ks * 4 + p];
                    float e0 = env * __builtin_amdgcn_exp2f(a.x);
                    float e1 = env * __builtin_amdgcn_exp2f(a.y);
                    v[2 * p]     = f2bf(e0);
                    v[2 * p + 1] = f2bf(e1);
                }
                bfrag[ks] = v;
            }

            // layer 0: D[ch][pair] += W0^T . E^T   (fp32 accumulate)
            f32x4 acc = {0.0f, 0.0f, 0.0f, 0.0f};
            acc = __builtin_amdgcn_mfma_f32_16x16x32_bf16(w0f[k][0], bfrag[0], acc, 0, 0, 0);
            acc = __builtin_amdgcn_mfma_f32_16x16x32_bf16(w0f[k][1], bfrag[1], acc, 0, 0, 0);

            // bias + ssp -> bf16 B-fragment for layer 1 (channel = g*4+e matches k-slot)
            bf16x8 hb = {0, 0, 0, 0, 0, 0, 0, 0};
            #pragma unroll
            for (int r = 0; r < 4; ++r)
                hb[r] = f2bf(ssp(acc[r] + b0v[k][r]));

            // layer 1: D2[e_out][pair] = W1^T . H1s  (K padded to 32)
            f32x4 a2 = {0.0f, 0.0f, 0.0f, 0.0f};
            a2 = __builtin_amdgcn_mfma_f32_16x16x32_bf16(w1f[k], hb, a2, 0, 0, 0);

            // rows 0..3 (= e_out) live in lanes 0..15; finish w and scale diff in place
            if (g == 0) {
                float w = ssp(a2[0] + b1k[0]) * W2k[0];
                w = fmaf(ssp(a2[1] + b1k[1]), W2k[1], w);
                w = fmaf(ssp(a2[2] + b1k[2]), W2k[2], w);
                w = fmaf(ssp(a2[3] + b1k[3]), W2k[3], w);
                int p = t * 16 + col;
                f32x4 df = s_df[q][p];
                s_df[q][p] = (f32x4){w * df.x, w * df.y, w * df.z, 0.0f};
            }
        }

        // ---- scatter-reduce: xs[e] += sum_j +/- w*diff ----
        if (lane < 45) {
            int e = lane / 3, dim = lane - 3 * e;
            const float* wd = (const float*)&s_df[q][0];
            float acc = 0.0f;
            int offe = e * (2 * N_EL - e - 1) / 2;
            for (int j = e + 1; j < N_EL; ++j)
                acc += wd[(offe + j - e - 1) * 4 + dim];
            for (int i2 = 0; i2 < e; ++i2) {
                int p = i2 * (2 * N_EL - i2 - 1) / 2 + (e - i2 - 1);
                acc -= wd[p * 4 + dim];
            }
            s_xs[q][lane] += acc;
        }
    }

    if (lane < 45) out[prob * 45 + lane] = s_xs[q][lane];
}

extern "C" void kernel_launch(void* const* d_in, const int* in_sizes, int n_in,
                              void* d_out, int out_size, void* d_ws, size_t ws_size,
                              hipStream_t stream) {
    const float* rs = (const float*)d_in[0];
    const float* W0 = (const float*)d_in[1];
    const float* b0 = (const float*)d_in[2];
    const float* W1 = (const float*)d_in[3];
    const float* b1 = (const float*)d_in[4];
    const float* W2 = (const float*)d_in[5];
    float* out = (float*)d_out;

    const int nprob = 4096 * 2;                   // (batch, spin) problems
    dim3 grid(nprob / WPB);                       // 2048 blocks
    dim3 block(NTHR);
    hipLaunchKernelGGL(backflow_kernel, grid, block, 0, stream,
                       rs, W0, b0, W1, b1, W2, out);
}

// Round 7
// 63.932 us; speedup vs baseline: 2.3848x; 1.2672x over previous
//
#include <hip/hip_runtime.h>

#define N_EL   15
#define NPAIR  105
#define NPAD   112
#define BASIS  64
#define CUTOFF 10.0f
#define LOG2E  1.44269504088896340736f
#define LN2    0.69314718055994530942f
#define WPB    4        // waves (= problems) per block
#define NTHR   256

typedef float f32x2 __attribute__((ext_vector_type(2)));
typedef float f32x4 __attribute__((ext_vector_type(4)));
typedef short bf16x8 __attribute__((ext_vector_type(8)));
typedef int   i32x4  __attribute__((ext_vector_type(4)));

// fp32 -> bf16 RNE (prologue only)
__device__ __forceinline__ short f2bf(float f) {
    unsigned u = __builtin_bit_cast(unsigned, f);
    u += 0x7FFFu + ((u >> 16) & 1u);
    return (short)(u >> 16);
}

// packed 2xf32 -> 2xbf16 (RNE), one instruction (guide T12 recipe, m214v22-proven)
__device__ __forceinline__ int cvt_pk_bf16(float lo, float hi) {
    int r;
    asm("v_cvt_pk_bf16_f32 %0, %1, %2" : "=v"(r) : "v"(lo), "v"(hi));
    return r;
}

// shifted softplus: log(0.5 + 0.5*e^x)  (R3/R4-proven form)
__device__ __forceinline__ float ssp(float x) {
    float u = __builtin_amdgcn_exp2f(x * LOG2E);
    return LN2 * __builtin_amdgcn_logf(fmaf(0.5f, u, 0.5f));
}

__global__ __launch_bounds__(NTHR, 4)
void backflow_kernel(const float* __restrict__ rs,
                     const float* __restrict__ W0,
                     const float* __restrict__ b0,
                     const float* __restrict__ W1,
                     const float* __restrict__ b1,
                     const float* __restrict__ W2,
                     float* __restrict__ out) {
    // per-wave private LDS (wave-synchronous; no __syncthreads anywhere)
    __shared__ f32x2 s_dd[WPB][NPAD];   // (dist, env) per pair
    __shared__ f32x4 s_df[WPB][NPAD];   // (dx,dy,dz,_) -> overwritten by w*diff
    __shared__ f32x4 s_h2[WPB][NPAD];   // raw layer-1 MFMA output per pair
    __shared__ float s_xs[WPB][48];     // coordinates

    const int tid  = threadIdx.x;
    const int q    = tid >> 6;          // wave within block
    const int lane = tid & 63;
    const int g    = lane >> 4;         // 4-lane group
    const int col  = lane & 15;
    const int prob = blockIdx.x * WPB + q;

    // ---- per-lane basis constants: dim(ks,e) = ks*32 + (e>>2)*16 + g*4 + (e&3) ----
    f32x2 mu2[8], is2[8];               // [ks*4 + p], elem pair (2p, 2p+1)
    #pragma unroll
    for (int ks = 0; ks < 2; ++ks)
        #pragma unroll
        for (int p = 0; p < 4; ++p) {
            f32x2 m, s;
            #pragma unroll
            for (int h = 0; h < 2; ++h) {
                int dim = ks * 32 + (p >> 1) * 16 + g * 4 + (p & 1) * 2 + h;
                float qq = (float)(2 * dim + 1) * (1.0f / 128.0f);
                m[h] = CUTOFF * qq * qq;
                float sg = fmaf(CUTOFF, qq, 1.0f) * (1.0f / 7.0f);
                s[h] = -LOG2E / (sg * sg);
            }
            mu2[ks * 4 + p] = m;
            is2[ks * 4 + p] = s;
        }

    // ---- resident weight fragments (bf16) ----
    bf16x8 w0f[3][2];   // A = W0^T : lane holds W0[dim(ks,e)][col]
    bf16x8 w1f[3];      // A = W1^T padded to K=32
    f32x4  b0v[3];      // raw b0[g*4 + 0..3]
    #pragma unroll
    for (int k = 0; k < 3; ++k) {
        #pragma unroll
        for (int ks = 0; ks < 2; ++ks) {
            bf16x8 v;
            #pragma unroll
            for (int e = 0; e < 8; ++e) {
                int dim = ks * 32 + (e >> 2) * 16 + g * 4 + (e & 3);
                v[e] = f2bf(W0[(k * BASIS + dim) * 16 + col]);
            }
            w0f[k][ks] = v;
        }
        bf16x8 v1;
        #pragma unroll
        for (int e = 0; e < 8; ++e) {
            int c = g * 4 + (e & 3);
            float wv = (e < 4 && col < 4) ? W1[(k * 16 + c) * 4 + col] : 0.0f;
            v1[e] = f2bf(wv);
        }
        w1f[k] = v1;
        b0v[k] = *(const f32x4*)(b0 + k * 16 + g * 4);
    }

    // ---- pair decode: p0 = lane, p1 = 64+lane (lane < 41) ----
    int pi0, pj0, pi1 = 0, pj1 = 0;
    {
        int t = lane, i = 0;
        while (t >= N_EL - 1 - i) { t -= N_EL - 1 - i; ++i; }
        pi0 = i; pj0 = i + 1 + t;
    }
    if (lane < 41) {
        int t = 64 + lane, i = 0;
        while (t >= N_EL - 1 - i) { t -= N_EL - 1 - i; ++i; }
        pi1 = i; pj1 = i + 1 + t;
    }

    if (lane < 45) s_xs[q][lane] = rs[prob * 45 + lane];

    for (int k = 0; k < 3; ++k) {
        const float* b1k = b1 + k * 4;
        const float* W2k = W2 + k * 4;

        // ---- dist/env/diff phase (R4-proven: env stored as multiplier) ----
        {
            float dx = s_xs[q][pj0 * 3 + 0] - s_xs[q][pi0 * 3 + 0];
            float dy = s_xs[q][pj0 * 3 + 1] - s_xs[q][pi0 * 3 + 1];
            float dz = s_xs[q][pj0 * 3 + 2] - s_xs[q][pi0 * 3 + 2];
            float dist = sqrtf(fmaf(dx, dx, fmaf(dy, dy, dz * dz)));
            float x = dist * (1.0f / CUTOFF);
            float env = 0.0f;
            if (x <= 1.0f) {
                float pp = fmaf(-6.0f, x, 15.0f);
                pp = fmaf(pp, x, -10.0f);
                env = fmaf(x * x * x, pp, 1.0f);
            }
            s_dd[q][lane] = (f32x2){dist, env};
            s_df[q][lane] = (f32x4){dx, dy, dz, 0.0f};
        }
        if (lane < 48) {
            if (lane < 41) {
                int p = 64 + lane;
                float dx = s_xs[q][pj1 * 3 + 0] - s_xs[q][pi1 * 3 + 0];
                float dy = s_xs[q][pj1 * 3 + 1] - s_xs[q][pi1 * 3 + 1];
                float dz = s_xs[q][pj1 * 3 + 2] - s_xs[q][pi1 * 3 + 2];
                float dist = sqrtf(fmaf(dx, dx, fmaf(dy, dy, dz * dz)));
                float x = dist * (1.0f / CUTOFF);
                float env = 0.0f;
                if (x <= 1.0f) {
                    float pp = fmaf(-6.0f, x, 15.0f);
                    pp = fmaf(pp, x, -10.0f);
                    env = fmaf(x * x * x, pp, 1.0f);
                }
                s_dd[q][p] = (f32x2){dist, env};
                s_df[q][p] = (f32x4){dx, dy, dz, 0.0f};
            } else {
                s_dd[q][64 + lane] = (f32x2){2.0f * CUTOFF, 0.0f};
            }
        }

        // ---- 7 tiles of 16 pairs ----
        for (int t = 0; t < 7; ++t) {
            f32x2 de = s_dd[q][t * 16 + col];
            float dist = de.x, env = de.y;
            f32x2 d2 = {dist, dist};

            bf16x8 bfrag[2];
            #pragma unroll
            for (int ks = 0; ks < 2; ++ks) {
                i32x4 wd;
                #pragma unroll
                for (int p = 0; p < 4; ++p) {
                    f32x2 tt = d2 - mu2[ks * 4 + p];
                    f32x2 a  = (tt * tt) * is2[ks * 4 + p];
                    float e0 = env * __builtin_amdgcn_exp2f(a.x);
                    float e1 = env * __builtin_amdgcn_exp2f(a.y);
                    wd[p] = cvt_pk_bf16(e0, e1);
                }
                bfrag[ks] = __builtin_bit_cast(bf16x8, wd);
            }

            // layer 0: D[ch][pair] = W0^T . E^T  (fp32 accumulate)
            f32x4 acc = {0.0f, 0.0f, 0.0f, 0.0f};
            acc = __builtin_amdgcn_mfma_f32_16x16x32_bf16(w0f[k][0], bfrag[0], acc, 0, 0, 0);
            acc = __builtin_amdgcn_mfma_f32_16x16x32_bf16(w0f[k][1], bfrag[1], acc, 0, 0, 0);

            // bias+ssp -> bf16 B-fragment for layer 1
            i32x4 hw;
            hw[0] = cvt_pk_bf16(ssp(acc[0] + b0v[k][0]), ssp(acc[1] + b0v[k][1]));
            hw[1] = cvt_pk_bf16(ssp(acc[2] + b0v[k][2]), ssp(acc[3] + b0v[k][3]));
            hw[2] = 0; hw[3] = 0;
            bf16x8 hb = __builtin_bit_cast(bf16x8, hw);

            // layer 1: D2[e_out][pair] = W1^T . H1s
            f32x4 a2 = {0.0f, 0.0f, 0.0f, 0.0f};
            a2 = __builtin_amdgcn_mfma_f32_16x16x32_bf16(w1f[k], hb, a2, 0, 0, 0);

            if (g == 0) s_h2[q][t * 16 + col] = a2;   // raw; finished in batch below
        }

        // ---- batched epilogue: w = sum_r ssp(a2[r]+b1[r])*W2[r]; s_df *= w ----
        #pragma unroll
        for (int it = 0; it < 2; ++it) {
            int p = it * 64 + lane;
            if (it == 0 || lane < 41) {
                f32x4 a2 = s_h2[q][p];
                float w = ssp(a2[0] + b1k[0]) * W2k[0];
                w = fmaf(ssp(a2[1] + b1k[1]), W2k[1], w);
                w = fmaf(ssp(a2[2] + b1k[2]), W2k[2], w);
                w = fmaf(ssp(a2[3] + b1k[3]), W2k[3], w);
                f32x4 df = s_df[q][p];
                s_df[q][p] = (f32x4){w * df.x, w * df.y, w * df.z, 0.0f};
            }
        }

        // ---- scatter-reduce: xs[e] += sum_j +/- w*diff ----
        if (lane < 45) {
            int e = lane / 3, dim = lane - 3 * e;
            const float* wd = (const float*)&s_df[q][0];
            float acc = 0.0f;
            int offe = e * (2 * N_EL - e - 1) / 2;
            for (int j = e + 1; j < N_EL; ++j)
                acc += wd[(offe + j - e - 1) * 4 + dim];
            for (int i2 = 0; i2 < e; ++i2) {
                int p = i2 * (2 * N_EL - i2 - 1) / 2 + (e - i2 - 1);
                acc -= wd[p * 4 + dim];
            }
            s_xs[q][lane] += acc;
        }
    }

    if (lane < 45) out[prob * 45 + lane] = s_xs[q][lane];
}

extern "C" void kernel_launch(void* const* d_in, const int* in_sizes, int n_in,
                              void* d_out, int out_size, void* d_ws, size_t ws_size,
                              hipStream_t stream) {
    const float* rs = (const float*)d_in[0];
    const float* W0 = (const float*)d_in[1];
    const float* b0 = (const float*)d_in[2];
    const float* W1 = (const float*)d_in[3];
    const float* b1 = (const float*)d_in[4];
    const float* W2 = (const float*)d_in[5];
    float* out = (float*)d_out;

    const int nprob = 4096 * 2;                   // (batch, spin) problems
    dim3 grid(nprob / WPB);                       // 2048 blocks
    dim3 block(NTHR);
    hipLaunchKernelGGL(backflow_kernel, grid, block, 0, stream,
                       rs, W0, b0, W1, b1, W2, out);
}

// Round 8
// 58.858 us; speedup vs baseline: 2.5904x; 1.0862x over previous
//
#include <hip/hip_runtime.h>

#define N_EL   15
#define NPAIR  105
#define NPAD   112
#define BASIS  64
#define CUTOFF 10.0f
#define LOG2E  1.44269504088896340736f
#define LN2    0.69314718055994530942f
#define WPB    4        // waves (= problems) per block
#define NTHR   256

typedef float f32x2 __attribute__((ext_vector_type(2)));
typedef float f32x4 __attribute__((ext_vector_type(4)));
typedef short bf16x8 __attribute__((ext_vector_type(8)));
typedef int   i32x4  __attribute__((ext_vector_type(4)));

// packed 2xf32 -> 2xbf16 (RNE), one instruction
__device__ __forceinline__ int cvt_pk_bf16(float lo, float hi) {
    int r;
    asm("v_cvt_pk_bf16_f32 %0, %1, %2" : "=v"(r) : "v"(lo), "v"(hi));
    return r;
}

// shifted softplus: log(0.5 + 0.5*e^x)
__device__ __forceinline__ float ssp(float x) {
    float u = __builtin_amdgcn_exp2f(x * LOG2E);
    return LN2 * __builtin_amdgcn_logf(fmaf(0.5f, u, 0.5f));
}

__global__ __launch_bounds__(NTHR, 4)
void backflow_kernel(const float* __restrict__ rs,
                     const float* __restrict__ W0,
                     const float* __restrict__ b0,
                     const float* __restrict__ W1,
                     const float* __restrict__ b1,
                     const float* __restrict__ W2,
                     float* __restrict__ out) {
    // per-wave private LDS (wave-synchronous; no __syncthreads anywhere)
    __shared__ f32x2 s_dd[WPB][NPAD];   // (dist, env) per pair
    __shared__ f32x4 s_df[WPB][NPAD];   // (dx,dy,dz,_) -> overwritten by w*diff
    __shared__ f32x4 s_h2[WPB][NPAD];   // raw layer-1 MFMA output per pair
    __shared__ float s_xs[WPB][48];     // coordinates

    const int tid  = threadIdx.x;
    const int q    = tid >> 6;          // wave within block
    const int lane = tid & 63;
    const int g    = lane >> 4;         // 4-lane group
    const int col  = lane & 15;
    const int prob = blockIdx.x * WPB + q;

    // ---- per-lane basis constants: dim(ks,e) = ks*32 + (e>>2)*16 + g*4 + (e&3) ----
    f32x2 mu2[8], is2[8];               // [ks*4 + p], elem pair (2p, 2p+1)
    #pragma unroll
    for (int ks = 0; ks < 2; ++ks)
        #pragma unroll
        for (int p = 0; p < 4; ++p) {
            f32x2 m, s;
            #pragma unroll
            for (int h = 0; h < 2; ++h) {
                int dim = ks * 32 + (p >> 1) * 16 + g * 4 + (p & 1) * 2 + h;
                float qq = (float)(2 * dim + 1) * (1.0f / 128.0f);
                m[h] = CUTOFF * qq * qq;
                float sg = fmaf(CUTOFF, qq, 1.0f) * (1.0f / 7.0f);
                s[h] = -LOG2E / (sg * sg);
            }
            mu2[ks * 4 + p] = m;
            is2[ks * 4 + p] = s;
        }

    // ---- pair decode: p0 = lane, p1 = 64+lane (lane < 41) ----
    int pi0, pj0, pi1 = 0, pj1 = 0;
    {
        int t = lane, i = 0;
        while (t >= N_EL - 1 - i) { t -= N_EL - 1 - i; ++i; }
        pi0 = i; pj0 = i + 1 + t;
    }
    if (lane < 41) {
        int t = 64 + lane, i = 0;
        while (t >= N_EL - 1 - i) { t -= N_EL - 1 - i; ++i; }
        pi1 = i; pj1 = i + 1 + t;
    }

    if (lane < 45) s_xs[q][lane] = rs[prob * 45 + lane];

    for (int k = 0; k < 3; ++k) {
        // ---- per-interaction weight fragments (L2-hot reload; frees VGPRs) ----
        bf16x8 w0f[2];      // A = W0^T : lane holds W0[dim(ks,e)][col]
        #pragma unroll
        for (int ks = 0; ks < 2; ++ks) {
            i32x4 wv;
            #pragma unroll
            for (int i = 0; i < 4; ++i) {
                int e0 = 2 * i, e1 = 2 * i + 1;
                int dim0 = ks * 32 + (e0 >> 2) * 16 + g * 4 + (e0 & 3);
                int dim1 = ks * 32 + (e1 >> 2) * 16 + g * 4 + (e1 & 3);
                float f0 = W0[(k * BASIS + dim0) * 16 + col];
                float f1 = W0[(k * BASIS + dim1) * 16 + col];
                wv[i] = cvt_pk_bf16(f0, f1);
            }
            w0f[ks] = __builtin_bit_cast(bf16x8, wv);
        }
        bf16x8 w1f;         // A = W1^T padded to K=32 (elems e>=4 zero)
        {
            i32x4 wv;
            float a0 = (col < 4) ? W1[(k * 16 + g * 4 + 0) * 4 + col] : 0.0f;
            float a1 = (col < 4) ? W1[(k * 16 + g * 4 + 1) * 4 + col] : 0.0f;
            float a2 = (col < 4) ? W1[(k * 16 + g * 4 + 2) * 4 + col] : 0.0f;
            float a3 = (col < 4) ? W1[(k * 16 + g * 4 + 3) * 4 + col] : 0.0f;
            wv[0] = cvt_pk_bf16(a0, a1);
            wv[1] = cvt_pk_bf16(a2, a3);
            wv[2] = 0; wv[3] = 0;
            w1f = __builtin_bit_cast(bf16x8, wv);
        }
        f32x4 b0v = *(const f32x4*)(b0 + k * 16 + g * 4);
        const float* b1k = b1 + k * 4;
        const float* W2k = W2 + k * 4;

        // ---- dist/env/diff phase ----
        {
            float dx = s_xs[q][pj0 * 3 + 0] - s_xs[q][pi0 * 3 + 0];
            float dy = s_xs[q][pj0 * 3 + 1] - s_xs[q][pi0 * 3 + 1];
            float dz = s_xs[q][pj0 * 3 + 2] - s_xs[q][pi0 * 3 + 2];
            float dist = sqrtf(fmaf(dx, dx, fmaf(dy, dy, dz * dz)));
            float x = dist * (1.0f / CUTOFF);
            float env = 0.0f;
            if (x <= 1.0f) {
                float pp = fmaf(-6.0f, x, 15.0f);
                pp = fmaf(pp, x, -10.0f);
                env = fmaf(x * x * x, pp, 1.0f);
            }
            s_dd[q][lane] = (f32x2){dist, env};
            s_df[q][lane] = (f32x4){dx, dy, dz, 0.0f};
        }
        if (lane < 48) {
            if (lane < 41) {
                int p = 64 + lane;
                float dx = s_xs[q][pj1 * 3 + 0] - s_xs[q][pi1 * 3 + 0];
                float dy = s_xs[q][pj1 * 3 + 1] - s_xs[q][pi1 * 3 + 1];
                float dz = s_xs[q][pj1 * 3 + 2] - s_xs[q][pi1 * 3 + 2];
                float dist = sqrtf(fmaf(dx, dx, fmaf(dy, dy, dz * dz)));
                float x = dist * (1.0f / CUTOFF);
                float env = 0.0f;
                if (x <= 1.0f) {
                    float pp = fmaf(-6.0f, x, 15.0f);
                    pp = fmaf(pp, x, -10.0f);
                    env = fmaf(x * x * x, pp, 1.0f);
                }
                s_dd[q][p] = (f32x2){dist, env};
                s_df[q][p] = (f32x4){dx, dy, dz, 0.0f};
            } else {
                s_dd[q][64 + lane] = (f32x2){2.0f * CUTOFF, 0.0f};
            }
        }

        // ---- 7 tiles of 16 pairs ----
        for (int t = 0; t < 7; ++t) {
            f32x2 de = s_dd[q][t * 16 + col];
            float env = de.y;
            f32x2 d2 = {de.x, de.x};

            // basis WITHOUT env (env applied to the MFMA output instead)
            bf16x8 bfrag[2];
            #pragma unroll
            for (int ks = 0; ks < 2; ++ks) {
                i32x4 wd;
                #pragma unroll
                for (int p = 0; p < 4; ++p) {
                    f32x2 tt = d2 - mu2[ks * 4 + p];
                    f32x2 a  = (tt * tt) * is2[ks * 4 + p];
                    float e0 = __builtin_amdgcn_exp2f(a.x);
                    float e1 = __builtin_amdgcn_exp2f(a.y);
                    wd[p] = cvt_pk_bf16(e0, e1);
                }
                bfrag[ks] = __builtin_bit_cast(bf16x8, wd);
            }

            // layer 0: D[ch][pair] = W0^T . E^T  (fp32 accumulate)
            f32x4 acc = {0.0f, 0.0f, 0.0f, 0.0f};
            acc = __builtin_amdgcn_mfma_f32_16x16x32_bf16(w0f[0], bfrag[0], acc, 0, 0, 0);
            acc = __builtin_amdgcn_mfma_f32_16x16x32_bf16(w0f[1], bfrag[1], acc, 0, 0, 0);

            // h1 = ssp(env*acc + b0) -> bf16 B-fragment (env fold = free fma)
            i32x4 hw;
            hw[0] = cvt_pk_bf16(ssp(fmaf(env, acc[0], b0v[0])),
                                ssp(fmaf(env, acc[1], b0v[1])));
            hw[1] = cvt_pk_bf16(ssp(fmaf(env, acc[2], b0v[2])),
                                ssp(fmaf(env, acc[3], b0v[3])));
            hw[2] = 0; hw[3] = 0;   // K=16..31 must be numeric (0*NaN = NaN)
            bf16x8 hb = __builtin_bit_cast(bf16x8, hw);

            // layer 1: D2[e_out][pair] = W1^T . H1s
            f32x4 a2 = {0.0f, 0.0f, 0.0f, 0.0f};
            a2 = __builtin_amdgcn_mfma_f32_16x16x32_bf16(w1f, hb, a2, 0, 0, 0);

            if (g == 0) s_h2[q][t * 16 + col] = a2;   // raw; finished in batch below
        }

        // ---- batched epilogue: w = sum_r ssp(a2[r]+b1[r])*W2[r]; s_df *= w ----
        #pragma unroll
        for (int it = 0; it < 2; ++it) {
            int p = it * 64 + lane;
            if (it == 0 || lane < 41) {
                f32x4 a2 = s_h2[q][p];
                float w = ssp(a2[0] + b1k[0]) * W2k[0];
                w = fmaf(ssp(a2[1] + b1k[1]), W2k[1], w);
                w = fmaf(ssp(a2[2] + b1k[2]), W2k[2], w);
                w = fmaf(ssp(a2[3] + b1k[3]), W2k[3], w);
                f32x4 df = s_df[q][p];
                s_df[q][p] = (f32x4){w * df.x, w * df.y, w * df.z, 0.0f};
            }
        }

        // ---- scatter-reduce: xs[e] += sum_j +/- w*diff ----
        if (lane < 45) {
            int e = lane / 3, dim = lane - 3 * e;
            const float* wd = (const float*)&s_df[q][0];
            float acc = 0.0f;
            int offe = e * (2 * N_EL - e - 1) / 2;
            for (int j = e + 1; j < N_EL; ++j)
                acc += wd[(offe + j - e - 1) * 4 + dim];
            for (int i2 = 0; i2 < e; ++i2) {
                int p = i2 * (2 * N_EL - i2 - 1) / 2 + (e - i2 - 1);
                acc -= wd[p * 4 + dim];
            }
            s_xs[q][lane] += acc;
        }
    }

    if (lane < 45) out[prob * 45 + lane] = s_xs[q][lane];
}

extern "C" void kernel_launch(void* const* d_in, const int* in_sizes, int n_in,
                              void* d_out, int out_size, void* d_ws, size_t ws_size,
                              hipStream_t stream) {
    const float* rs = (const float*)d_in[0];
    const float* W0 = (const float*)d_in[1];
    const float* b0 = (const float*)d_in[2];
    const float* W1 = (const float*)d_in[3];
    const float* b1 = (const float*)d_in[4];
    const float* W2 = (const float*)d_in[5];
    float* out = (float*)d_out;

    const int nprob = 4096 * 2;                   // (batch, spin) problems
    dim3 grid(nprob / WPB);                       // 2048 blocks
    dim3 block(NTHR);
    hipLaunchKernelGGL(backflow_kernel, grid, block, 0, stream,
                       rs, W0, b0, W1, b1, W2, out);
}